// Round 11
// baseline (98.920 us; speedup 1.0000x reference)
//
#include <hip/hip_runtime.h>

#define DIN  128
#define DOUT 32

typedef __attribute__((ext_vector_type(8))) short bf16x8;   // 8 bf16 = 4 VGPRs
typedef __attribute__((ext_vector_type(4))) float f32x4;

// f32 -> bf16 (RNE), manual
__device__ __forceinline__ unsigned int f2b(float f) {
    unsigned int u = __float_as_uint(f);
    return (u + 0x7fffu + ((u >> 16) & 1u)) >> 16;
}
// packed f32x2 -> bf16x2 (RNE), hardware
__device__ __forceinline__ unsigned int cvtpk(float lo, float hi) {
    unsigned int r;
    asm("v_cvt_pk_bf16_f32 %0, %1, %2" : "=v"(r) : "v"(lo), "v"(hi));
    return r;
}

union FragU { bf16x8 v; unsigned int u[4]; };

// ---- B fragments from W (built once; W is L1/L2-hot) -----------------------
__device__ __forceinline__ void build_bfrag(const float* __restrict__ W,
                                            int lane, bf16x8 bfrag[2][4])
{
    const int lr = lane & 15, kh = lane >> 4;
    #pragma unroll
    for (int ct = 0; ct < 2; ++ct) {
        #pragma unroll
        for (int ks = 0; ks < 4; ++ks) {
            const int col = ct * 16 + lr;
            const int k0  = ks * 32 + kh * 8;
            float f[8];
            #pragma unroll
            for (int j = 0; j < 8; ++j) f[j] = W[(k0 + j) * DOUT + col];
            FragU fu;
            fu.u[0] = cvtpk(f[0], f[1]); fu.u[1] = cvtpk(f[2], f[3]);
            fu.u[2] = cvtpk(f[4], f[5]); fu.u[3] = cvtpk(f[6], f[7]);
            bfrag[ct][ks] = fu.v;
        }
    }
}

// ---------------- DIAG Kernel 1: GEMM body x4 -------------------------------
// Identical per-rep body to the round-10 gemm_tile. Memory clobber between
// reps forces the H loads to re-issue; keep-alive asm stops DCE of reps 0-2.
// Divide this dispatch's dur by 4 for the true GEMM time. Rep scaling:
// linear => latency/issue-bound; sub-linear => HBM-BW-bound (reps hit LLC).
__global__ __launch_bounds__(256) void gemm_diag4(
    const float* __restrict__ H, const float* __restrict__ W,
    unsigned short* __restrict__ HWb, int n)
{
    const int lane = threadIdx.x & 63;
    const int w    = threadIdx.x >> 6;
    bf16x8 bfrag[2][4];
    build_bfrag(W, lane, bfrag);

    int rb = blockIdx.x * 64 + w * 16;
    if (rb + 16 > n) rb = n - 16;      // tail overlap: identical values, benign
    const int lr = lane & 15, kh = lane >> 4;
    const float* __restrict__ hp = H + (size_t)(rb + lr) * DIN;

    f32x4 acc[2];
    for (int rep = 0; rep < 4; ++rep) {
        asm volatile("" ::: "memory");         // force reload of H each rep
        float4 raw[8];
        #pragma unroll
        for (int ks = 0; ks < 4; ++ks) {
            raw[2*ks]   = *reinterpret_cast<const float4*>(hp + ks * 32 + kh * 8);
            raw[2*ks+1] = *reinterpret_cast<const float4*>(hp + ks * 32 + kh * 8 + 4);
        }
        bf16x8 afrag[4];
        #pragma unroll
        for (int ks = 0; ks < 4; ++ks) {
            FragU fu;
            fu.u[0] = cvtpk(raw[2*ks].x,   raw[2*ks].y);
            fu.u[1] = cvtpk(raw[2*ks].z,   raw[2*ks].w);
            fu.u[2] = cvtpk(raw[2*ks+1].x, raw[2*ks+1].y);
            fu.u[3] = cvtpk(raw[2*ks+1].z, raw[2*ks+1].w);
            afrag[ks] = fu.v;
        }
        acc[0] = (f32x4){0.f,0.f,0.f,0.f};
        acc[1] = (f32x4){0.f,0.f,0.f,0.f};
        #pragma unroll
        for (int ct = 0; ct < 2; ++ct)
            #pragma unroll
            for (int ks = 0; ks < 4; ++ks)
                acc[ct] = __builtin_amdgcn_mfma_f32_16x16x32_bf16(
                    afrag[ks], bfrag[ct][ks], acc[ct], 0, 0, 0);
        if (rep < 3) {
            asm volatile("" ::
                "v"(acc[0][0]), "v"(acc[0][1]), "v"(acc[0][2]), "v"(acc[0][3]),
                "v"(acc[1][0]), "v"(acc[1][1]), "v"(acc[1][2]), "v"(acc[1][3]));
        }
    }

    #pragma unroll
    for (int ct = 0; ct < 2; ++ct)
        #pragma unroll
        for (int r = 0; r < 4; ++r)
            HWb[(size_t)(rb + kh * 4 + r) * DOUT + ct * 16 + lr] =
                (unsigned short)f2b(acc[ct][r]);
}

// ---------------- DIAG Kernel 2: SpMM body x4 -------------------------------
// Identical per-rep body to round-10 spmm_row (batched 16-gather fast path).
// VALUBusy>40% => issue-bound; low VALUBusy + small FETCH + linear scaling
// => gather latency/throughput wall on the cached table.
__global__ __launch_bounds__(256) void spmm_diag4(
    const unsigned short* __restrict__ HWb, const int* __restrict__ rowPtr,
    const int* __restrict__ colIdx, const float* __restrict__ val,
    float* __restrict__ out, int n)
{
    const int gid = blockIdx.x * 256 + threadIdx.x;
    const int row = gid >> 3;
    if (row >= n) return;
    const int cg = gid & 7;

    const uint2* __restrict__ tbl = reinterpret_cast<const uint2*>(HWb);
    const int start = rowPtr[row];
    const int end   = rowPtr[row + 1];
    float a0, a1, a2, a3;

    #define ACC(G, V)                                                        \
        a0 = fmaf(V, __uint_as_float((G).x << 16), a0);                      \
        a1 = fmaf(V, __uint_as_float((G).x & 0xffff0000u), a1);              \
        a2 = fmaf(V, __uint_as_float((G).y << 16), a2);                      \
        a3 = fmaf(V, __uint_as_float((G).y & 0xffff0000u), a3);

    for (int rep = 0; rep < 4; ++rep) {
        asm volatile("" ::: "memory");       // force re-gather each rep
        a0 = a1 = a2 = a3 = 0.f;
        if (end - start == 16 && (start & 3) == 0) {
            const int4*   ci = reinterpret_cast<const int4*>(colIdx + start);
            const float4* vv = reinterpret_cast<const float4*>(val + start);
            const int4   c0 = ci[0], c1 = ci[1], c2 = ci[2], c3 = ci[3];
            const float4 v0 = vv[0], v1 = vv[1], v2 = vv[2], v3 = vv[3];
            const uint2 g0  = tbl[c0.x * 8 + cg], g1  = tbl[c0.y * 8 + cg];
            const uint2 g2  = tbl[c0.z * 8 + cg], g3  = tbl[c0.w * 8 + cg];
            const uint2 g4  = tbl[c1.x * 8 + cg], g5  = tbl[c1.y * 8 + cg];
            const uint2 g6  = tbl[c1.z * 8 + cg], g7  = tbl[c1.w * 8 + cg];
            const uint2 g8  = tbl[c2.x * 8 + cg], g9  = tbl[c2.y * 8 + cg];
            const uint2 g10 = tbl[c2.z * 8 + cg], g11 = tbl[c2.w * 8 + cg];
            const uint2 g12 = tbl[c3.x * 8 + cg], g13 = tbl[c3.y * 8 + cg];
            const uint2 g14 = tbl[c3.z * 8 + cg], g15 = tbl[c3.w * 8 + cg];
            ACC(g0,  v0.x) ACC(g1,  v0.y) ACC(g2,  v0.z) ACC(g3,  v0.w)
            ACC(g4,  v1.x) ACC(g5,  v1.y) ACC(g6,  v1.z) ACC(g7,  v1.w)
            ACC(g8,  v2.x) ACC(g9,  v2.y) ACC(g10, v2.z) ACC(g11, v2.w)
            ACC(g12, v3.x) ACC(g13, v3.y) ACC(g14, v3.z) ACC(g15, v3.w)
        } else {
            for (int e = start; e < end; ++e) {
                const int   c = colIdx[e];
                const float v = val[e];
                const uint2 g = tbl[c * 8 + cg];
                ACC(g, v)
            }
        }
        if (rep < 3)
            asm volatile("" :: "v"(a0), "v"(a1), "v"(a2), "v"(a3));
    }
    #undef ACC

    reinterpret_cast<float4*>(out)[(size_t)row * 8 + cg] =
        make_float4(a0, a1, a2, a3);
}

// ---------------- Fallback: fused f32 (ws too small or n < 16) --------------
__global__ __launch_bounds__(256) void fused_kernel(
    const float* __restrict__ H, const float* __restrict__ W,
    const int* __restrict__ rowPtr, const int* __restrict__ colIdx,
    const float* __restrict__ val, float* __restrict__ out, int n)
{
    __shared__ float Wlds[DIN * DOUT];
    for (int i = threadIdx.x; i < DIN * DOUT; i += 256) Wlds[i] = W[i];
    __syncthreads();

    const int gid = blockIdx.x * 256 + threadIdx.x;
    const int row = gid >> 5;
    if (row >= n) return;
    const int c = gid & 31;

    const int start = rowPtr[row];
    const int end   = rowPtr[row + 1];
    float acc = 0.f;
    for (int e = start; e < end; ++e) {
        const int   cidx = colIdx[e];
        const float v    = val[e];
        const float* h = H + (size_t)cidx * DIN;
        float dot = 0.f;
        #pragma unroll 8
        for (int k = 0; k < DIN; ++k)
            dot = fmaf(h[k], Wlds[k * DOUT + c], dot);
        acc = fmaf(v, dot, acc);
    }
    out[(size_t)row * DOUT + c] = acc;
}

extern "C" void kernel_launch(void* const* d_in, const int* in_sizes, int n_in,
                              void* d_out, int out_size, void* d_ws, size_t ws_size,
                              hipStream_t stream)
{
    const float* H      = (const float*)d_in[0];
    const float* W      = (const float*)d_in[1];
    const int*   rowPtr = (const int*)d_in[2];
    const int*   colIdx = (const int*)d_in[3];
    const float* val    = (const float*)d_in[4];
    float*       out    = (float*)d_out;

    const int n = in_sizes[2] - 1;           // rowPtr has N+1 entries
    const size_t hw_bytes = (size_t)n * DOUT * sizeof(unsigned short);

    if (ws_size >= hw_bytes && n >= 16) {
        unsigned short* HWb = (unsigned short*)d_ws;
        gemm_diag4<<<(n + 63) / 64, 256, 0, stream>>>(H, W, HWb, n);
        const int spmm_blocks = (int)(((size_t)n * 8 + 255) / 256);
        spmm_diag4<<<spmm_blocks, 256, 0, stream>>>(HWb, rowPtr, colIdx, val, out, n);
    } else {
        const int blocks = (int)(((size_t)n * DOUT + 255) / 256);
        fused_kernel<<<blocks, 256, 0, stream>>>(H, W, rowPtr, colIdx, val, out, n);
    }
}

// Round 12
// 55.622 us; speedup vs baseline: 1.7784x; 1.7784x over previous
//
#include <hip/hip_runtime.h>

#define DIN  128
#define DOUT 32
#define NSLICE 4            // 4 column-slices x 8 cols; slice table = N*16B

typedef __attribute__((ext_vector_type(8))) short bf16x8;   // 8 bf16 = 4 VGPRs
typedef __attribute__((ext_vector_type(4))) float f32x4;

// f32 -> bf16 (RNE), manual
__device__ __forceinline__ unsigned int f2b(float f) {
    unsigned int u = __float_as_uint(f);
    return (u + 0x7fffu + ((u >> 16) & 1u)) >> 16;
}
// packed f32x2 -> bf16x2 (RNE), hardware
__device__ __forceinline__ unsigned int cvtpk(float lo, float hi) {
    unsigned int r;
    asm("v_cvt_pk_bf16_f32 %0, %1, %2" : "=v"(r) : "v"(lo), "v"(hi));
    return r;
}

union FragU { bf16x8 v; unsigned int u[4]; };

// ---- B fragments from W (built once; W is L1/L2-hot) -----------------------
__device__ __forceinline__ void build_bfrag(const float* __restrict__ W,
                                            int lane, bf16x8 bfrag[2][4])
{
    const int lr = lane & 15, kh = lane >> 4;
    #pragma unroll
    for (int ct = 0; ct < 2; ++ct) {
        #pragma unroll
        for (int ks = 0; ks < 4; ++ks) {
            const int col = ct * 16 + lr;
            const int k0  = ks * 32 + kh * 8;
            float f[8];
            #pragma unroll
            for (int j = 0; j < 8; ++j) f[j] = W[(k0 + j) * DOUT + col];
            FragU fu;
            fu.u[0] = cvtpk(f[0], f[1]); fu.u[1] = cvtpk(f[2], f[3]);
            fu.u[2] = cvtpk(f[4], f[5]); fu.u[3] = cvtpk(f[6], f[7]);
            bfrag[ct][ks] = fu.v;
        }
    }
}

// ---------------- Kernel 1: sliced bf16 table = H @ W via MFMA --------------
// Structure identical to the round-10 GEMM (diag: ~9 us/rep, ~stream floor).
// Store goes to the column-sliced layout: slice s holds cols [8s, 8s+8) of
// all rows, contiguously: tbl16[(s*n + row)*8 + (col&7)].
__global__ __launch_bounds__(256) void gemm_mfma_kernel(
    const float* __restrict__ H, const float* __restrict__ W,
    unsigned short* __restrict__ tbl16, int n)
{
    const int lane = threadIdx.x & 63;
    const int w    = threadIdx.x >> 6;
    bf16x8 bfrag[2][4];
    build_bfrag(W, lane, bfrag);

    int rb = blockIdx.x * 64 + w * 16;
    if (rb + 16 > n) rb = n - 16;      // tail overlap: identical values, benign
    const int lr = lane & 15, kh = lane >> 4;
    const float* __restrict__ hp = H + (size_t)(rb + lr) * DIN;

    float4 raw[8];
    #pragma unroll
    for (int ks = 0; ks < 4; ++ks) {
        raw[2*ks]   = *reinterpret_cast<const float4*>(hp + ks * 32 + kh * 8);
        raw[2*ks+1] = *reinterpret_cast<const float4*>(hp + ks * 32 + kh * 8 + 4);
    }
    bf16x8 afrag[4];
    #pragma unroll
    for (int ks = 0; ks < 4; ++ks) {
        FragU fu;
        fu.u[0] = cvtpk(raw[2*ks].x,   raw[2*ks].y);
        fu.u[1] = cvtpk(raw[2*ks].z,   raw[2*ks].w);
        fu.u[2] = cvtpk(raw[2*ks+1].x, raw[2*ks+1].y);
        fu.u[3] = cvtpk(raw[2*ks+1].z, raw[2*ks+1].w);
        afrag[ks] = fu.v;
    }

    f32x4 acc[2] = {(f32x4){0.f,0.f,0.f,0.f}, (f32x4){0.f,0.f,0.f,0.f}};
    #pragma unroll
    for (int ct = 0; ct < 2; ++ct)
        #pragma unroll
        for (int ks = 0; ks < 4; ++ks)
            acc[ct] = __builtin_amdgcn_mfma_f32_16x16x32_bf16(
                afrag[ks], bfrag[ct][ks], acc[ct], 0, 0, 0);

    // C/D: col = ct*16+lr, row = rb + kh*4 + r  ->  sliced store
    #pragma unroll
    for (int ct = 0; ct < 2; ++ct) {
        const int col = ct * 16 + lr;
        const int s   = col >> 3;          // 0..3
        const int c8  = col & 7;
        #pragma unroll
        for (int r = 0; r < 4; ++r) {
            const int row = rb + kh * 4 + r;
            tbl16[((size_t)s * n + row) * 8 + c8] = (unsigned short)f2b(acc[ct][r]);
        }
    }
}

// ---------------- Kernel 2: XCD-pinned slice SpMM ---------------------------
// grid = nrowblk * NSLICE, slice = blockIdx & 3 -> round-robin dispatch pins
// each slice (1.6 MB) to fixed XCDs: gathers become L2 hits instead of 8x
// duplicated random fabric traffic. One thread per row: streams its 16
// (idx,val) contiguously, gathers 16 x uint4 (16B row-slice), writes 8 f32.
__global__ __launch_bounds__(256) void spmm_slice_kernel(
    const unsigned short* __restrict__ tbl16, const int* __restrict__ rowPtr,
    const int* __restrict__ colIdx, const float* __restrict__ val,
    float* __restrict__ out, int n)
{
    const int s      = blockIdx.x & (NSLICE - 1);
    const int rowblk = blockIdx.x >> 2;
    const int row    = rowblk * 256 + threadIdx.x;
    if (row >= n) return;

    const uint4* __restrict__ t4 =
        reinterpret_cast<const uint4*>(tbl16) + (size_t)s * n;

    const int start = rowPtr[row];
    const int end   = rowPtr[row + 1];
    float a0=0,a1=0,a2=0,a3=0,a4=0,a5=0,a6=0,a7=0;

    #define ACC(G, V)                                                        \
        a0 = fmaf(V, __uint_as_float((G).x << 16), a0);                      \
        a1 = fmaf(V, __uint_as_float((G).x & 0xffff0000u), a1);              \
        a2 = fmaf(V, __uint_as_float((G).y << 16), a2);                      \
        a3 = fmaf(V, __uint_as_float((G).y & 0xffff0000u), a3);              \
        a4 = fmaf(V, __uint_as_float((G).z << 16), a4);                      \
        a5 = fmaf(V, __uint_as_float((G).z & 0xffff0000u), a5);              \
        a6 = fmaf(V, __uint_as_float((G).w << 16), a6);                      \
        a7 = fmaf(V, __uint_as_float((G).w & 0xffff0000u), a7);

    if (end - start == 16 && (start & 3) == 0) {
        const int4*   ci = reinterpret_cast<const int4*>(colIdx + start);
        const float4* vv = reinterpret_cast<const float4*>(val + start);
        const int4   c0 = ci[0], c1 = ci[1], c2 = ci[2], c3 = ci[3];
        const float4 v0 = vv[0], v1 = vv[1], v2 = vv[2], v3 = vv[3];
        const uint4 g0  = t4[c0.x], g1  = t4[c0.y], g2  = t4[c0.z], g3  = t4[c0.w];
        const uint4 g4  = t4[c1.x], g5  = t4[c1.y], g6  = t4[c1.z], g7  = t4[c1.w];
        const uint4 g8  = t4[c2.x], g9  = t4[c2.y], g10 = t4[c2.z], g11 = t4[c2.w];
        const uint4 g12 = t4[c3.x], g13 = t4[c3.y], g14 = t4[c3.z], g15 = t4[c3.w];
        ACC(g0,  v0.x) ACC(g1,  v0.y) ACC(g2,  v0.z) ACC(g3,  v0.w)
        ACC(g4,  v1.x) ACC(g5,  v1.y) ACC(g6,  v1.z) ACC(g7,  v1.w)
        ACC(g8,  v2.x) ACC(g9,  v2.y) ACC(g10, v2.z) ACC(g11, v2.w)
        ACC(g12, v3.x) ACC(g13, v3.y) ACC(g14, v3.z) ACC(g15, v3.w)
    } else {
        for (int e = start; e < end; ++e) {
            const int   c = colIdx[e];
            const float v = val[e];
            const uint4 g = t4[c];
            ACC(g, v)
        }
    }
    #undef ACC

    float4* __restrict__ op =
        reinterpret_cast<float4*>(out) + (size_t)row * 8 + s * 2;
    op[0] = make_float4(a0, a1, a2, a3);
    op[1] = make_float4(a4, a5, a6, a7);
}

// ---------------- Fallback: fused f32 (ws too small or n < 16) --------------
__global__ __launch_bounds__(256) void fused_kernel(
    const float* __restrict__ H, const float* __restrict__ W,
    const int* __restrict__ rowPtr, const int* __restrict__ colIdx,
    const float* __restrict__ val, float* __restrict__ out, int n)
{
    __shared__ float Wlds[DIN * DOUT];
    for (int i = threadIdx.x; i < DIN * DOUT; i += 256) Wlds[i] = W[i];
    __syncthreads();

    const int gid = blockIdx.x * 256 + threadIdx.x;
    const int row = gid >> 5;
    if (row >= n) return;
    const int c = gid & 31;

    const int start = rowPtr[row];
    const int end   = rowPtr[row + 1];
    float acc = 0.f;
    for (int e = start; e < end; ++e) {
        const int   cidx = colIdx[e];
        const float v    = val[e];
        const float* h = H + (size_t)cidx * DIN;
        float dot = 0.f;
        #pragma unroll 8
        for (int k = 0; k < DIN; ++k)
            dot = fmaf(h[k], Wlds[k * DOUT + c], dot);
        acc = fmaf(v, dot, acc);
    }
    out[(size_t)row * DOUT + c] = acc;
}

extern "C" void kernel_launch(void* const* d_in, const int* in_sizes, int n_in,
                              void* d_out, int out_size, void* d_ws, size_t ws_size,
                              hipStream_t stream)
{
    const float* H      = (const float*)d_in[0];
    const float* W      = (const float*)d_in[1];
    const int*   rowPtr = (const int*)d_in[2];
    const int*   colIdx = (const int*)d_in[3];
    const float* val    = (const float*)d_in[4];
    float*       out    = (float*)d_out;

    const int n = in_sizes[2] - 1;           // rowPtr has N+1 entries
    const size_t hw_bytes = (size_t)n * DOUT * sizeof(unsigned short);

    if (ws_size >= hw_bytes && n >= 16) {
        unsigned short* tbl16 = (unsigned short*)d_ws;
        gemm_mfma_kernel<<<(n + 63) / 64, 256, 0, stream>>>(H, W, tbl16, n);
        const int nrowblk = (n + 255) / 256;
        spmm_slice_kernel<<<nrowblk * NSLICE, 256, 0, stream>>>(
            tbl16, rowPtr, colIdx, val, out, n);
    } else {
        const int blocks = (int)(((size_t)n * DOUT + 255) / 256);
        fused_kernel<<<blocks, 256, 0, stream>>>(H, W, rowPtr, colIdx, val, out, n);
    }
}

// Round 13
// 41.792 us; speedup vs baseline: 2.3670x; 1.3309x over previous
//
#include <hip/hip_runtime.h>

#define DIN  128
#define DOUT 32

typedef __attribute__((ext_vector_type(8))) short bf16x8;   // 8 bf16 = 4 VGPRs
typedef __attribute__((ext_vector_type(4))) float f32x4;

// f32 -> bf16 (RNE), manual
__device__ __forceinline__ unsigned int f2b(float f) {
    unsigned int u = __float_as_uint(f);
    return (u + 0x7fffu + ((u >> 16) & 1u)) >> 16;
}
// packed f32x2 -> bf16x2 (RNE), hardware
__device__ __forceinline__ unsigned int cvtpk(float lo, float hi) {
    unsigned int r;
    asm("v_cvt_pk_bf16_f32 %0, %1, %2" : "=v"(r) : "v"(lo), "v"(hi));
    return r;
}

union FragU { bf16x8 v; unsigned int u[4]; };

// ---- B fragments from W (built once; W is L1/L2-hot) -----------------------
__device__ __forceinline__ void build_bfrag(const float* __restrict__ W,
                                            int lane, bf16x8 bfrag[2][4])
{
    const int lr = lane & 15, kh = lane >> 4;
    #pragma unroll
    for (int ct = 0; ct < 2; ++ct) {
        #pragma unroll
        for (int ks = 0; ks < 4; ++ks) {
            const int col = ct * 16 + lr;
            const int k0  = ks * 32 + kh * 8;
            float f[8];
            #pragma unroll
            for (int j = 0; j < 8; ++j) f[j] = W[(k0 + j) * DOUT + col];
            FragU fu;
            fu.u[0] = cvtpk(f[0], f[1]); fu.u[1] = cvtpk(f[2], f[3]);
            fu.u[2] = cvtpk(f[4], f[5]); fu.u[3] = cvtpk(f[6], f[7]);
            bfrag[ct][ks] = fu.v;
        }
    }
}

// ---------------- Kernel 1: 2-slice bf16 table = H @ W via MFMA -------------
// GEMM structure proven at ~stream floor (R11 diag). Store: slice s = ct
// holds cols [16s,16s+16) contiguously: tbl[(s*n + row)*16 + (col&15)].
// Slice = 3.2 MB -> fits a 4 MB per-XCD L2 (the 6.4 MB full table never did).
__global__ __launch_bounds__(256) void gemm_mfma_kernel(
    const float* __restrict__ H, const float* __restrict__ W,
    unsigned short* __restrict__ tbl, int n)
{
    const int lane = threadIdx.x & 63;
    const int w    = threadIdx.x >> 6;
    bf16x8 bfrag[2][4];
    build_bfrag(W, lane, bfrag);

    int rb = blockIdx.x * 64 + w * 16;
    if (rb + 16 > n) rb = n - 16;      // tail overlap: identical values, benign
    const int lr = lane & 15, kh = lane >> 4;
    const float* __restrict__ hp = H + (size_t)(rb + lr) * DIN;

    float4 raw[8];
    #pragma unroll
    for (int ks = 0; ks < 4; ++ks) {
        raw[2*ks]   = *reinterpret_cast<const float4*>(hp + ks * 32 + kh * 8);
        raw[2*ks+1] = *reinterpret_cast<const float4*>(hp + ks * 32 + kh * 8 + 4);
    }
    bf16x8 afrag[4];
    #pragma unroll
    for (int ks = 0; ks < 4; ++ks) {
        FragU fu;
        fu.u[0] = cvtpk(raw[2*ks].x,   raw[2*ks].y);
        fu.u[1] = cvtpk(raw[2*ks].z,   raw[2*ks].w);
        fu.u[2] = cvtpk(raw[2*ks+1].x, raw[2*ks+1].y);
        fu.u[3] = cvtpk(raw[2*ks+1].z, raw[2*ks+1].w);
        afrag[ks] = fu.v;
    }

    f32x4 acc[2] = {(f32x4){0.f,0.f,0.f,0.f}, (f32x4){0.f,0.f,0.f,0.f}};
    #pragma unroll
    for (int ct = 0; ct < 2; ++ct)
        #pragma unroll
        for (int ks = 0; ks < 4; ++ks)
            acc[ct] = __builtin_amdgcn_mfma_f32_16x16x32_bf16(
                afrag[ks], bfrag[ct][ks], acc[ct], 0, 0, 0);

    // C/D: col = ct*16+lr -> slice ct, col-in-slice lr; row = rb + kh*4 + r
    #pragma unroll
    for (int ct = 0; ct < 2; ++ct) {
        #pragma unroll
        for (int r = 0; r < 4; ++r) {
            const int row = rb + kh * 4 + r;
            tbl[((size_t)ct * n + row) * 16 + lr] = (unsigned short)f2b(acc[ct][r]);
        }
    }
}

// ---------------- Kernel 2: 2-slice SpMM (R10 issue structure) --------------
// slice = blockIdx&1: even XCDs serve slice 0, odd slice 1 (round-robin
// dispatch). Per XCD: one 3.2 MB L2-resident slice -> fill 25.6 MB total
// (vs 51 MB duplicated). 4 thr/row x uint2(8B): wave-gather = 16 random
// contiguous 32B chunks (high line utilization, R10-proven). 16 gathers
// batched before consumption; ascending-edge accumulation order.
__global__ __launch_bounds__(256) void spmm_slice2_kernel(
    const unsigned short* __restrict__ tbl, const int* __restrict__ rowPtr,
    const int* __restrict__ colIdx, const float* __restrict__ val,
    float* __restrict__ out, int n)
{
    const int s   = blockIdx.x & 1;
    const int gid = (blockIdx.x >> 1) * 256 + threadIdx.x;
    const int row = gid >> 2;
    if (row >= n) return;
    const int cg  = gid & 3;

    const uint2* __restrict__ t2 =
        reinterpret_cast<const uint2*>(tbl) + (size_t)s * n * 4;

    const int start = rowPtr[row];
    const int end   = rowPtr[row + 1];
    float a0 = 0.f, a1 = 0.f, a2 = 0.f, a3 = 0.f;

    #define ACC(G, V)                                                        \
        a0 = fmaf(V, __uint_as_float((G).x << 16), a0);                      \
        a1 = fmaf(V, __uint_as_float((G).x & 0xffff0000u), a1);              \
        a2 = fmaf(V, __uint_as_float((G).y << 16), a2);                      \
        a3 = fmaf(V, __uint_as_float((G).y & 0xffff0000u), a3);

    if (end - start == 16 && (start & 3) == 0) {
        const int4*   ci = reinterpret_cast<const int4*>(colIdx + start);
        const float4* vv = reinterpret_cast<const float4*>(val + start);
        const int4   c0 = ci[0], c1 = ci[1], c2 = ci[2], c3 = ci[3];
        const float4 v0 = vv[0], v1 = vv[1], v2 = vv[2], v3 = vv[3];
        const uint2 g0  = t2[(size_t)c0.x * 4 + cg], g1  = t2[(size_t)c0.y * 4 + cg];
        const uint2 g2  = t2[(size_t)c0.z * 4 + cg], g3  = t2[(size_t)c0.w * 4 + cg];
        const uint2 g4  = t2[(size_t)c1.x * 4 + cg], g5  = t2[(size_t)c1.y * 4 + cg];
        const uint2 g6  = t2[(size_t)c1.z * 4 + cg], g7  = t2[(size_t)c1.w * 4 + cg];
        const uint2 g8  = t2[(size_t)c2.x * 4 + cg], g9  = t2[(size_t)c2.y * 4 + cg];
        const uint2 g10 = t2[(size_t)c2.z * 4 + cg], g11 = t2[(size_t)c2.w * 4 + cg];
        const uint2 g12 = t2[(size_t)c3.x * 4 + cg], g13 = t2[(size_t)c3.y * 4 + cg];
        const uint2 g14 = t2[(size_t)c3.z * 4 + cg], g15 = t2[(size_t)c3.w * 4 + cg];
        ACC(g0,  v0.x) ACC(g1,  v0.y) ACC(g2,  v0.z) ACC(g3,  v0.w)
        ACC(g4,  v1.x) ACC(g5,  v1.y) ACC(g6,  v1.z) ACC(g7,  v1.w)
        ACC(g8,  v2.x) ACC(g9,  v2.y) ACC(g10, v2.z) ACC(g11, v2.w)
        ACC(g12, v3.x) ACC(g13, v3.y) ACC(g14, v3.z) ACC(g15, v3.w)
    } else {
        for (int e = start; e < end; ++e) {
            const int   c = colIdx[e];
            const float v = val[e];
            const uint2 g = t2[(size_t)c * 4 + cg];
            ACC(g, v)
        }
    }
    #undef ACC

    reinterpret_cast<float4*>(out)[(size_t)row * 8 + s * 4 + cg] =
        make_float4(a0, a1, a2, a3);
}

// ---------------- Fallback: fused f32 (ws too small or n < 16) --------------
__global__ __launch_bounds__(256) void fused_kernel(
    const float* __restrict__ H, const float* __restrict__ W,
    const int* __restrict__ rowPtr, const int* __restrict__ colIdx,
    const float* __restrict__ val, float* __restrict__ out, int n)
{
    __shared__ float Wlds[DIN * DOUT];
    for (int i = threadIdx.x; i < DIN * DOUT; i += 256) Wlds[i] = W[i];
    __syncthreads();

    const int gid = blockIdx.x * 256 + threadIdx.x;
    const int row = gid >> 5;
    if (row >= n) return;
    const int c = gid & 31;

    const int start = rowPtr[row];
    const int end   = rowPtr[row + 1];
    float acc = 0.f;
    for (int e = start; e < end; ++e) {
        const int   cidx = colIdx[e];
        const float v    = val[e];
        const float* h = H + (size_t)cidx * DIN;
        float dot = 0.f;
        #pragma unroll 8
        for (int k = 0; k < DIN; ++k)
            dot = fmaf(h[k], Wlds[k * DOUT + c], dot);
        acc = fmaf(v, dot, acc);
    }
    out[(size_t)row * DOUT + c] = acc;
}

extern "C" void kernel_launch(void* const* d_in, const int* in_sizes, int n_in,
                              void* d_out, int out_size, void* d_ws, size_t ws_size,
                              hipStream_t stream)
{
    const float* H      = (const float*)d_in[0];
    const float* W      = (const float*)d_in[1];
    const int*   rowPtr = (const int*)d_in[2];
    const int*   colIdx = (const int*)d_in[3];
    const float* val    = (const float*)d_in[4];
    float*       out    = (float*)d_out;

    const int n = in_sizes[2] - 1;           // rowPtr has N+1 entries
    const size_t hw_bytes = (size_t)n * DOUT * sizeof(unsigned short);

    if (ws_size >= hw_bytes && n >= 16) {
        unsigned short* tbl = (unsigned short*)d_ws;
        gemm_mfma_kernel<<<(n + 63) / 64, 256, 0, stream>>>(H, W, tbl, n);
        const int nrowblk = (n + 63) / 64;     // 64 rows per block-slice
        spmm_slice2_kernel<<<nrowblk * 2, 256, 0, stream>>>(
            tbl, rowPtr, colIdx, val, out, n);
    } else {
        const int blocks = (int)(((size_t)n * DOUT + 255) / 256);
        fused_kernel<<<blocks, 256, 0, stream>>>(H, W, rowPtr, colIdx, val, out, n);
    }
}

// Round 14
// 38.073 us; speedup vs baseline: 2.5982x; 1.0977x over previous
//
#include <hip/hip_runtime.h>

#define DIN  128
#define DOUT 32

typedef __attribute__((ext_vector_type(8))) short bf16x8;   // 8 bf16 = 4 VGPRs
typedef __attribute__((ext_vector_type(4))) float f32x4;

// f32 -> bf16 (RNE), manual
__device__ __forceinline__ unsigned int f2b(float f) {
    unsigned int u = __float_as_uint(f);
    return (u + 0x7fffu + ((u >> 16) & 1u)) >> 16;
}
// packed f32x2 -> bf16x2 (RNE), hardware
__device__ __forceinline__ unsigned int cvtpk(float lo, float hi) {
    unsigned int r;
    asm("v_cvt_pk_bf16_f32 %0, %1, %2" : "=v"(r) : "v"(lo), "v"(hi));
    return r;
}

union FragU { bf16x8 v; unsigned int u[4]; };

// ---- B fragments from W (built once; W is L1/L2-hot) -----------------------
__device__ __forceinline__ void build_bfrag(const float* __restrict__ W,
                                            int lane, bf16x8 bfrag[2][4])
{
    const int lr = lane & 15, kh = lane >> 4;
    #pragma unroll
    for (int ct = 0; ct < 2; ++ct) {
        #pragma unroll
        for (int ks = 0; ks < 4; ++ks) {
            const int col = ct * 16 + lr;
            const int k0  = ks * 32 + kh * 8;
            float f[8];
            #pragma unroll
            for (int j = 0; j < 8; ++j) f[j] = W[(k0 + j) * DOUT + col];
            FragU fu;
            fu.u[0] = cvtpk(f[0], f[1]); fu.u[1] = cvtpk(f[2], f[3]);
            fu.u[2] = cvtpk(f[4], f[5]); fu.u[3] = cvtpk(f[6], f[7]);
            bfrag[ct][ks] = fu.v;
        }
    }
}

// ---- one 16-row GEMM tile via MFMA; all 8 loads issued before any cvt ------
__device__ __forceinline__ void gemm_tile(const float* __restrict__ H,
                                          unsigned short* __restrict__ HWb,
                                          int rb, int lane,
                                          const bf16x8 bfrag[2][4])
{
    const int lr = lane & 15, kh = lane >> 4;
    const float* __restrict__ hp = H + (size_t)(rb + lr) * DIN;

    float4 raw[8];
    #pragma unroll
    for (int ks = 0; ks < 4; ++ks) {
        raw[2*ks]   = *reinterpret_cast<const float4*>(hp + ks * 32 + kh * 8);
        raw[2*ks+1] = *reinterpret_cast<const float4*>(hp + ks * 32 + kh * 8 + 4);
    }
    bf16x8 afrag[4];
    #pragma unroll
    for (int ks = 0; ks < 4; ++ks) {
        FragU fu;
        fu.u[0] = cvtpk(raw[2*ks].x,   raw[2*ks].y);
        fu.u[1] = cvtpk(raw[2*ks].z,   raw[2*ks].w);
        fu.u[2] = cvtpk(raw[2*ks+1].x, raw[2*ks+1].y);
        fu.u[3] = cvtpk(raw[2*ks+1].z, raw[2*ks+1].w);
        afrag[ks] = fu.v;
    }

    f32x4 acc[2] = {(f32x4){0.f,0.f,0.f,0.f}, (f32x4){0.f,0.f,0.f,0.f}};
    #pragma unroll
    for (int ct = 0; ct < 2; ++ct)
        #pragma unroll
        for (int ks = 0; ks < 4; ++ks)
            acc[ct] = __builtin_amdgcn_mfma_f32_16x16x32_bf16(
                afrag[ks], bfrag[ct][ks], acc[ct], 0, 0, 0);

    #pragma unroll
    for (int ct = 0; ct < 2; ++ct)
        #pragma unroll
        for (int r = 0; r < 4; ++r)
            HWb[(size_t)(rb + kh * 4 + r) * DOUT + ct * 16 + lr] =
                (unsigned short)f2b(acc[ct][r]);
}

// ---- SpMM row body: 8 threads/row, 4 cols each; 16 gathers force-batched ---
__device__ __forceinline__ void spmm_row(const unsigned short* __restrict__ HWb,
                                         const int* __restrict__ rowPtr,
                                         const int* __restrict__ colIdx,
                                         const float* __restrict__ val,
                                         float* __restrict__ out,
                                         int n, int row, int cg)
{
    if (row >= n) return;
    const uint2* __restrict__ tbl = reinterpret_cast<const uint2*>(HWb);
    const int start = rowPtr[row];
    const int end   = rowPtr[row + 1];
    float a0 = 0.f, a1 = 0.f, a2 = 0.f, a3 = 0.f;

    #define ACC(G, V)                                                        \
        a0 = fmaf(V, __uint_as_float((G).x << 16), a0);                      \
        a1 = fmaf(V, __uint_as_float((G).x & 0xffff0000u), a1);              \
        a2 = fmaf(V, __uint_as_float((G).y << 16), a2);                      \
        a3 = fmaf(V, __uint_as_float((G).y & 0xffff0000u), a3);

    if (end - start == 16 && (start & 3) == 0) {
        const int4*   ci = reinterpret_cast<const int4*>(colIdx + start);
        const float4* vv = reinterpret_cast<const float4*>(val + start);
        const int4   c0 = ci[0], c1 = ci[1], c2 = ci[2], c3 = ci[3];
        const float4 v0 = vv[0], v1 = vv[1], v2 = vv[2], v3 = vv[3];
        // all 16 gathers issued before any consumption
        const uint2 g0  = tbl[c0.x * 8 + cg], g1  = tbl[c0.y * 8 + cg];
        const uint2 g2  = tbl[c0.z * 8 + cg], g3  = tbl[c0.w * 8 + cg];
        const uint2 g4  = tbl[c1.x * 8 + cg], g5  = tbl[c1.y * 8 + cg];
        const uint2 g6  = tbl[c1.z * 8 + cg], g7  = tbl[c1.w * 8 + cg];
        const uint2 g8  = tbl[c2.x * 8 + cg], g9  = tbl[c2.y * 8 + cg];
        const uint2 g10 = tbl[c2.z * 8 + cg], g11 = tbl[c2.w * 8 + cg];
        const uint2 g12 = tbl[c3.x * 8 + cg], g13 = tbl[c3.y * 8 + cg];
        const uint2 g14 = tbl[c3.z * 8 + cg], g15 = tbl[c3.w * 8 + cg];
        // reference accumulation order (ascending edge)
        ACC(g0,  v0.x) ACC(g1,  v0.y) ACC(g2,  v0.z) ACC(g3,  v0.w)
        ACC(g4,  v1.x) ACC(g5,  v1.y) ACC(g6,  v1.z) ACC(g7,  v1.w)
        ACC(g8,  v2.x) ACC(g9,  v2.y) ACC(g10, v2.z) ACC(g11, v2.w)
        ACC(g12, v3.x) ACC(g13, v3.y) ACC(g14, v3.z) ACC(g15, v3.w)
    } else {
        for (int e = start; e < end; ++e) {
            const int   c = colIdx[e];
            const float v = val[e];
            const uint2 g = tbl[c * 8 + cg];
            ACC(g, v)
        }
    }
    #undef ACC

    reinterpret_cast<float4*>(out)[(size_t)row * 8 + cg] =
        make_float4(a0, a1, a2, a3);
}

// ---------------- Kernel 1: HWb = bf16(H @ W) via MFMA ----------------------
__global__ __launch_bounds__(256) void gemm_mfma_kernel(
    const float* __restrict__ H, const float* __restrict__ W,
    unsigned short* __restrict__ HWb, int n)
{
    const int lane = threadIdx.x & 63;
    const int w    = threadIdx.x >> 6;
    bf16x8 bfrag[2][4];
    build_bfrag(W, lane, bfrag);
    int rb = blockIdx.x * 64 + w * 16;
    if (rb + 16 > n) rb = n - 16;      // tail overlap: identical values, benign
    gemm_tile(H, HWb, rb, lane, bfrag);
}

// ---------------- Kernel 2: out = A_csr @ HWb -------------------------------
__global__ __launch_bounds__(256) void spmm_kernel(
    const unsigned short* __restrict__ HWb, const int* __restrict__ rowPtr,
    const int* __restrict__ colIdx, const float* __restrict__ val,
    float* __restrict__ out, int n)
{
    const int gid = blockIdx.x * 256 + threadIdx.x;
    spmm_row(HWb, rowPtr, colIdx, val, out, n, gid >> 3, gid & 7);
}

// ---------------- Fallback: fused f32 (ws too small or n < 16) --------------
__global__ __launch_bounds__(256) void fused_kernel(
    const float* __restrict__ H, const float* __restrict__ W,
    const int* __restrict__ rowPtr, const int* __restrict__ colIdx,
    const float* __restrict__ val, float* __restrict__ out, int n)
{
    __shared__ float Wlds[DIN * DOUT];
    for (int i = threadIdx.x; i < DIN * DOUT; i += 256) Wlds[i] = W[i];
    __syncthreads();

    const int gid = blockIdx.x * 256 + threadIdx.x;
    const int row = gid >> 5;
    if (row >= n) return;
    const int c = gid & 31;

    const int start = rowPtr[row];
    const int end   = rowPtr[row + 1];
    float acc = 0.f;
    for (int e = start; e < end; ++e) {
        const int   cidx = colIdx[e];
        const float v    = val[e];
        const float* h = H + (size_t)cidx * DIN;
        float dot = 0.f;
        #pragma unroll 8
        for (int k = 0; k < DIN; ++k)
            dot = fmaf(h[k], Wlds[k * DOUT + c], dot);
        acc = fmaf(v, dot, acc);
    }
    out[(size_t)row * DOUT + c] = acc;
}

extern "C" void kernel_launch(void* const* d_in, const int* in_sizes, int n_in,
                              void* d_out, int out_size, void* d_ws, size_t ws_size,
                              hipStream_t stream)
{
    const float* H      = (const float*)d_in[0];
    const float* W      = (const float*)d_in[1];
    const int*   rowPtr = (const int*)d_in[2];
    const int*   colIdx = (const int*)d_in[3];
    const float* val    = (const float*)d_in[4];
    float*       out    = (float*)d_out;

    const int n = in_sizes[2] - 1;           // rowPtr has N+1 entries
    const size_t hw_bytes = (size_t)n * DOUT * sizeof(unsigned short);

    if (ws_size >= hw_bytes && n >= 16) {
        unsigned short* HWb = (unsigned short*)d_ws;
        gemm_mfma_kernel<<<(n + 63) / 64, 256, 0, stream>>>(H, W, HWb, n);
        const int spmm_blocks = (int)(((size_t)n * 8 + 255) / 256);
        spmm_kernel<<<spmm_blocks, 256, 0, stream>>>(HWb, rowPtr, colIdx, val, out, n);
    } else {
        const int blocks = (int)(((size_t)n * DOUT + 255) / 256);
        fused_kernel<<<blocks, 256, 0, stream>>>(H, W, rowPtr, colIdx, val, out, n);
    }
}